// Round 11
// baseline (3783.546 us; speedup 1.0000x reference)
//
#include <hip/hip_runtime.h>
#include <hip/hip_bf16.h>
#include <stdint.h>

#define T_STEPS 200
#define BATCH   256
#define NS      256   // states S
#define NA      16    // actions A
#define DOBS    128
#define DCTL    16
#define LOG2PI  1.8378770664093453f
#define EPS_F   1e-6f

typedef float f32x4 __attribute__((ext_vector_type(4)));
typedef short s16x8 __attribute__((ext_vector_type(8)));
typedef short s16x4 __attribute__((ext_vector_type(4)));

static __device__ __forceinline__ unsigned short f2bf(float f) {
    union { float f; unsigned u; } v; v.f = f;
    unsigned u = v.u;
    u += 0x7fffu + ((u >> 16) & 1u);   // RNE
    return (unsigned short)(u >> 16);
}

// ---- MALL-coherent (L1+L2 bypass) transport, canary-in-data (R7, proven) ----
static __device__ __forceinline__ void ld4_mall(const float* base,
                                                f32x4& a, f32x4& b, f32x4& c, f32x4& d) {
    asm volatile(
        "global_load_dwordx4 %0, %4, off offset:0 sc0 sc1\n\t"
        "global_load_dwordx4 %1, %4, off offset:1024 sc0 sc1\n\t"
        "global_load_dwordx4 %2, %4, off offset:2048 sc0 sc1\n\t"
        "global_load_dwordx4 %3, %4, off offset:3072 sc0 sc1\n\t"
        "s_waitcnt vmcnt(0)"
        : "=&v"(a), "=&v"(b), "=&v"(c), "=&v"(d)
        : "v"(base)
        : "memory");
}
static __device__ __forceinline__ void st_mall(float* p, f32x4 v) {
    asm volatile("global_store_dwordx4 %0, %1, off sc0 sc1" :: "v"(p), "v"(v) : "memory");
}

// ---- prep kernels (R7 set, proven) ----
__global__ __launch_bounds__(128) void k_prep_obs(const float* __restrict__ obs_mu,
                                                  const float* __restrict__ obs_lv,
                                                  float* __restrict__ WT,
                                                  float* __restrict__ Cs) {
    int s = blockIdx.x, d = threadIdx.x;
    float lv = obs_lv[s * DOBS + d];
    float mu = obs_mu[s * DOBS + d];
    float iv = expf(-lv);
    WT[d * NS + s]          = -0.5f * iv;
    WT[(DOBS + d) * NS + s] = mu * iv;
    float part = mu * mu * iv + lv;
    for (int m = 1; m < 64; m <<= 1) part += __shfl_xor(part, m, 64);
    __shared__ float red[2];
    if ((threadIdx.x & 63) == 0) red[threadIdx.x >> 6] = part;
    __syncthreads();
    if (threadIdx.x == 0) Cs[s] = -0.5f * (red[0] + red[1] + DOBS * LOG2PI);
}

__global__ __launch_bounds__(256) void k_prep_ctl(const float* __restrict__ cmu,
                                                  const float* __restrict__ clv,
                                                  float* __restrict__ cw1,
                                                  float* __restrict__ cw2,
                                                  float* __restrict__ cc) {
    int t = threadIdx.x;
    int a = t >> 4, d = t & 15;
    float lv = clv[a * DCTL + d];
    float mu = cmu[a * DCTL + d];
    float iv = expf(-lv);
    cw1[t] = -0.5f * iv;
    cw2[t] = mu * iv;
    float part = mu * mu * iv + lv;
    for (int m = 1; m < 16; m <<= 1) part += __shfl_xor(part, m, 64);
    if (d == 0) cc[a] = -0.5f * (part + DCTL * LOG2PI);
}

__global__ __launch_bounds__(64) void k_prep_pi0(const float* __restrict__ pl,
                                                 float* __restrict__ lpi0) {
    int l = threadIdx.x;
    float v[4]; float m = -1e30f;
    for (int k = 0; k < 4; k++) { v[k] = pl[l + 64 * k]; m = fmaxf(m, v[k]); }
    for (int mm = 1; mm < 64; mm <<= 1) m = fmaxf(m, __shfl_xor(m, mm, 64));
    float ssum = 0.f;
    for (int k = 0; k < 4; k++) ssum += expf(v[k] - m);
    for (int mm = 1; mm < 64; mm <<= 1) ssum += __shfl_xor(ssum, mm, 64);
    float ls = logf(ssum);
    for (int k = 0; k < 4; k++) lpi0[l + 64 * k] = v[k] - m - ls;
}

// NaN-fill the 4 rotating exchange buffers (MALL-visible)
__global__ __launch_bounds__(256) void k_init(float* __restrict__ lg) {
    int idx = blockIdx.x * 256 + threadIdx.x;
    float nv = __int_as_float(0x7FC00000);
    f32x4 n4 = {nv, nv, nv, nv};
    st_mall(lg + (size_t)idx * 4, n4);
}

__global__ __launch_bounds__(256) void k_trans(const float* __restrict__ tl,
                                               __hip_bfloat16* __restrict__ TRf) {
    int wave = threadIdx.x >> 6, lane = threadIdx.x & 63;
    int row = blockIdx.x * 4 + wave;        // (a,i) row in [0,4096)
    int a = row >> 8, i = row & 255;
    const float* src = tl + (size_t)row * NS;
    float v[4]; float m = -1e30f;
    for (int k = 0; k < 4; k++) { v[k] = src[lane + 64 * k]; m = fmaxf(m, v[k]); }
    for (int mm = 1; mm < 64; mm <<= 1) m = fmaxf(m, __shfl_xor(m, mm, 64));
    float ssum = 0.f; float ev[4];
    for (int k = 0; k < 4; k++) { ev[k] = expf(v[k] - m); ssum += ev[k]; }
    for (int mm = 1; mm < 64; mm <<= 1) ssum += __shfl_xor(ssum, mm, 64);
    float inv = 1.f / ssum;
    int kk = i >> 5;
    int lsub = ((i >> 3) & 3) * 16 + a;
    int e = i & 7;
    for (int k = 0; k < 4; k++) {
        int j = lane + 64 * k;
        float p = ev[k] * inv;
        TRf[((size_t)(j * 8 + kk) * 64 + lsub) * 8 + e] = __float2bfloat16(p);
    }
}

__global__ __launch_bounds__(64) void k_prep_ap(const float* __restrict__ ap,
                                                __hip_bfloat16* __restrict__ APh,
                                                __hip_bfloat16* __restrict__ APl) {
    int kk = blockIdx.x, lane = threadIdx.x;
    for (int e = 0; e < 8; e++) {
        int i = kk * 32 + (lane >> 4) * 8 + e;
        int a = lane & 15;
        float v = ap[i * NA + a];
        __hip_bfloat16 hb = __float2bfloat16(v);
        float hi = __bfloat162float(hb);
        APh[(kk * 64 + lane) * 8 + e] = hb;
        APl[(kk * 64 + lane) * 8 + e] = __float2bfloat16(v - hi);
    }
}

__global__ __launch_bounds__(256) void k_obslp(const float* __restrict__ x,
                                               const float* __restrict__ WT,
                                               const float* __restrict__ Cs,
                                               float* __restrict__ obs) {
    __shared__ float f[32 * 256];
    int r0 = blockIdx.x * 32;
    for (int idx = threadIdx.x; idx < 32 * DOBS; idx += 256) {
        int r = idx >> 7, d = idx & 127;
        float v = x[(size_t)(r0 + r) * DOBS + d];
        f[r * 256 + d] = v * v;
        f[r * 256 + 128 + d] = v;
    }
    __syncthreads();
    int s = threadIdx.x;
    float acc[32];
#pragma unroll
    for (int r = 0; r < 32; r++) acc[r] = 0.f;
    for (int d4 = 0; d4 < 64; d4++) {
        float w0 = WT[(d4 * 4 + 0) * NS + s];
        float w1 = WT[(d4 * 4 + 1) * NS + s];
        float w2 = WT[(d4 * 4 + 2) * NS + s];
        float w3 = WT[(d4 * 4 + 3) * NS + s];
#pragma unroll
        for (int r = 0; r < 32; r++) {
            f32x4 fv = *reinterpret_cast<const f32x4*>(&f[r * 256 + d4 * 4]);
            acc[r] += fv.x * w0 + fv.y * w1 + fv.z * w2 + fv.w * w3;
        }
    }
    float c = Cs[s];
#pragma unroll
    for (int r = 0; r < 32; r++) obs[(size_t)(r0 + r) * NS + s] = acc[r] + c;
}

__global__ __launch_bounds__(256) void k_ctllp(const float* __restrict__ u,
                                               const float* __restrict__ cw1,
                                               const float* __restrict__ cw2,
                                               const float* __restrict__ cc,
                                               float* __restrict__ ctl) {
    int idx = blockIdx.x * 256 + threadIdx.x;
    int r = idx >> 4, a = idx & 15;
    const float* ur = u + (size_t)r * DCTL;
    const float* w1 = cw1 + a * DCTL;
    const float* w2 = cw2 + a * DCTL;
    float acc = cc[a];
#pragma unroll
    for (int d = 0; d < 16; d++) {
        float uv = ur[d];
        acc += uv * uv * w1[d] + uv * w2[d];
    }
    ctl[idx] = acc;
}

// ================= persistent scan, time-staggered dual context =================
// 128 blocks x 256 threads. Block b owns ctxA = (bt = b>>4 in 0-7, jt = b&15)
// and ctxB = (bt+8, same jt) -> trans B-frags shared. Per step: A-phase then
// B-phase; while A's 16KB exchange propagates through the MALL, the block
// computes B's full phase — A's next gather then hits on the first retry.
// Canary-in-data protocol per bt-group exactly as R7 (proven).
struct ScanArgs {
    const float* obs;
    const float* ctlp;
    const float* lpi0;
    const __hip_bfloat16* TRf;
    const __hip_bfloat16* APh;
    const __hip_bfloat16* APl;
    float* lg;        // 4 x 65536 floats
    float* out_ab;
    float* out_aa;
};

struct Ctx {
    const float* obs_pf;   // obs row slice for t = s+1
    const float* ctl_p;    // ctl_lp slice for step s
    float*       ab_p;     // alpha_b out
    float*       aa_p;     // alpha_a out
    const float* obs0_p;   // obs[0] rows (step 0 init)
    const float* lg_ld;    // exchange gather base
    float*       lg_st;    // exchange store base
};

static __device__ __forceinline__ void scan_phase(
    int s, int jt, int lane, int wv, int kgrp, int arow, Ctx& C,
    const s16x8 (&bfr)[4][8], const s16x8 (&aph)[8], const s16x8 (&apl)[8],
    const f32x4& lp0, const f32x4& n4,
    char* PLb, float (*out_t)[16])
{
    // prefetch (cached loads, in flight across gather)
    f32x4 obs_pfv[4];
#pragma unroll
    for (int r = 0; r < 4; r++)
        obs_pfv[r] = *(const f32x4*)&C.obs_pf[r * NS];
    float ctl_pf[4];
#pragma unroll
    for (int q = 0; q < 4; q++)
        ctl_pf[q] = C.ctl_p[q * NA];

    // ---- gather l[s]: obs0+log_pi0 at s=0, else canary retry-load
    f32x4 V[4];
    if (s == 0) {
#pragma unroll
        for (int q = 0; q < 4; q++) {
            f32x4 o = *(const f32x4*)&C.obs0_p[q * NS];
            V[q] = o + lp0;
        }
    } else {
        const float* rb = C.lg_ld + ((size_t)(s & 3) << 16);
        for (;;) {
            ld4_mall(rb, V[0], V[1], V[2], V[3]);
            float chk = ((V[0].x + V[0].y) + (V[0].z + V[0].w))
                      + ((V[1].x + V[1].y) + (V[1].z + V[1].w))
                      + ((V[2].x + V[2].y) + (V[2].z + V[2].w))
                      + ((V[3].x + V[3].y) + (V[3].z + V[3].w));
            if (chk == chk) break;   // all finite -> all written
        }
    }

    // ---- recycle my tile in buf[(s+2)&3] (readers provably done; my own
    // later vmcnt(0)s order reset before the step-s+1 rewrite)
    if (s >= 2 && wv == 0)
        st_mall(C.lg_st + ((size_t)((s + 2) & 3) << 16), n4);

    // ---- phase 1: softmax -> p, alpha_b write, PLb (bf16, swizzled)
#pragma unroll
    for (int q = 0; q < 4; q++) {
        int r = wv * 4 + q;
        float m = fmaxf(fmaxf(V[q].x, V[q].y), fmaxf(V[q].z, V[q].w));
        for (int mm = 1; mm < 64; mm <<= 1) m = fmaxf(m, __shfl_xor(m, mm, 64));
        float e0 = __expf(V[q].x - m), e1 = __expf(V[q].y - m);
        float e2 = __expf(V[q].z - m), e3 = __expf(V[q].w - m);
        float ss = (e0 + e1) + (e2 + e3);
        for (int mm = 1; mm < 64; mm <<= 1) ss += __shfl_xor(ss, mm, 64);
        float inv = 1.f / ss;
        float p0 = e0 * inv, p1 = e1 * inv, p2 = e2 * inv, p3 = e3 * inv;
        if ((lane >> 2) == jt) {
            f32x4 pv = {p0, p1, p2, p3};
            *(f32x4*)&C.ab_p[q * NS] = pv;
        }
        s16x4 sv;
        sv[0] = (short)f2bf(p0); sv[1] = (short)f2bf(p1);
        sv[2] = (short)f2bf(p2); sv[3] = (short)f2bf(p3);
        *(s16x4*)(PLb + r * 512 + ((lane * 8) ^ ((r & 7) << 4))) = sv;
    }
    __syncthreads();

    // ---- A-fragments (swizzled b128 reads)
    s16x8 afr[8];
    {
        int sw = (arow & 7) << 4;
#pragma unroll
        for (int kk = 0; kk < 8; kk++)
            afr[kk] = *(const s16x8*)(PLb + arow * 512 + ((kk * 64 + kgrp * 16) ^ sw));
    }

    // ---- phase 3: g = p @ act_prior (hi+lo), a_t in-register
    f32x4 gh = {0.f, 0.f, 0.f, 0.f}, gl = {0.f, 0.f, 0.f, 0.f};
#pragma unroll
    for (int kk = 0; kk < 8; kk++) {
        gh = __builtin_amdgcn_mfma_f32_16x16x32_bf16(afr[kk], aph[kk], gh, 0, 0, 0);
        gl = __builtin_amdgcn_mfma_f32_16x16x32_bf16(afr[kk], apl[kk], gl, 0, 0, 0);
    }
    float at[4];
#pragma unroll
    for (int q = 0; q < 4; q++) {
        float gv = gh[q] + gl[q];
        float m = gv;
        for (int mm = 1; mm < 16; mm <<= 1) m = fmaxf(m, __shfl_xor(m, mm, 64));
        float e1 = __expf(gv - m);
        float s1 = e1;
        for (int mm = 1; mm < 16; mm <<= 1) s1 += __shfl_xor(s1, mm, 64);
        float apr = e1 / s1;
        float al = ctl_pf[q] + __logf(apr + EPS_F);
        float m2 = al;
        for (int mm = 1; mm < 16; mm <<= 1) m2 = fmaxf(m2, __shfl_xor(m2, mm, 64));
        float e2 = __expf(al - m2);
        float s2 = e2;
        for (int mm = 1; mm < 16; mm <<= 1) s2 += __shfl_xor(s2, mm, 64);
        at[q] = e2 / s2;
        if (jt == 0)
            C.aa_p[q * NA] = at[q];
    }

    // ---- phase 5: m2 = p @ trans, contract a_t -> out_t
#pragma unroll
    for (int q2 = 0; q2 < 4; q2++) {
        f32x4 acc = {0.f, 0.f, 0.f, 0.f};
#pragma unroll
        for (int kk = 0; kk < 8; kk++)
            acc = __builtin_amdgcn_mfma_f32_16x16x32_bf16(afr[kk], bfr[q2][kk], acc, 0, 0, 0);
#pragma unroll
        for (int r = 0; r < 4; r++) {
            float vv = acc[r] * at[r];
            for (int mm = 1; mm < 16; mm <<= 1) vv += __shfl_xor(vv, mm, 64);
            if (arow == 0)
                out_t[kgrp * 4 + r][wv * 4 + q2] =
                    obs_pfv[r][q2] + __logf(vv + NS * EPS_F);
        }
    }
    __syncthreads();

    // ---- wv0: gather rows and store next-step logits (fire-and-forget).
    // Safe vs next phase: out_t is only rewritten after the next barrier.
    if (wv == 0) {
        f32x4 val = *(const f32x4*)&out_t[lane >> 2][(lane & 3) * 4];
        st_mall(C.lg_st + ((size_t)((s + 1) & 3) << 16), val);
    }
    C.obs_pf += (size_t)BATCH * NS;
    C.ctl_p  += (size_t)BATCH * NA;
    C.ab_p   += (size_t)BATCH * NS;
    C.aa_p   += (size_t)BATCH * NA;
}

static __device__ __forceinline__ void final_softmax(
    int jt, int lane, const Ctx& C)
{
    f32x4 V[4];
    {
        const float* rb = C.lg_ld + ((size_t)((T_STEPS - 1) & 3) << 16);
        for (;;) {
            ld4_mall(rb, V[0], V[1], V[2], V[3]);
            float chk = ((V[0].x + V[0].y) + (V[0].z + V[0].w))
                      + ((V[1].x + V[1].y) + (V[1].z + V[1].w))
                      + ((V[2].x + V[2].y) + (V[2].z + V[2].w))
                      + ((V[3].x + V[3].y) + (V[3].z + V[3].w));
            if (chk == chk) break;
        }
    }
#pragma unroll
    for (int q = 0; q < 4; q++) {
        float m = fmaxf(fmaxf(V[q].x, V[q].y), fmaxf(V[q].z, V[q].w));
        for (int mm = 1; mm < 64; mm <<= 1) m = fmaxf(m, __shfl_xor(m, mm, 64));
        float e0 = __expf(V[q].x - m), e1 = __expf(V[q].y - m);
        float e2 = __expf(V[q].z - m), e3 = __expf(V[q].w - m);
        float ss = (e0 + e1) + (e2 + e3);
        for (int mm = 1; mm < 64; mm <<= 1) ss += __shfl_xor(ss, mm, 64);
        float inv = 1.f / ss;
        if ((lane >> 2) == jt) {
            f32x4 pv = {e0 * inv, e1 * inv, e2 * inv, e3 * inv};
            *(f32x4*)&C.ab_p[q * NS] = pv;   // ab_p points at t = T-1
        }
    }
}

__global__ __launch_bounds__(256, 1) void k_scan_p(ScanArgs A) {
    const int bid  = blockIdx.x;          // 0..127
    const int btA  = bid >> 4;            // 0..7
    const int btB  = btA + 8;             // 8..15
    const int jt   = bid & 15;
    const int tid  = threadIdx.x;
    const int wv   = tid >> 6, lane = tid & 63;
    const int kgrp = lane >> 4, arow = lane & 15;

    __shared__ __align__(16) char PLb[16 * 512];
    __shared__ float out_t[16][16];

    const float nv = __int_as_float(0x7FC00000);
    const f32x4 n4 = {nv, nv, nv, nv};

    // ---- preload constant fragments (shared: both contexts have the same jt)
    s16x8 bfr[4][8];
#pragma unroll
    for (int q = 0; q < 4; q++) {
        int ct = jt * 16 + wv * 4 + q;
#pragma unroll
        for (int kk = 0; kk < 8; kk++)
            bfr[q][kk] = *((const s16x8*)A.TRf + (size_t)(ct * 8 + kk) * 64 + lane);
    }
    s16x8 aph[8], apl[8];
#pragma unroll
    for (int kk = 0; kk < 8; kk++) {
        aph[kk] = *((const s16x8*)A.APh + kk * 64 + lane);
        apl[kk] = *((const s16x8*)A.APl + kk * 64 + lane);
    }
    f32x4 lp0 = *(const f32x4*)&A.lpi0[lane * 4];

    // ---- per-context pointers
    auto mkctx = [&](int bt) -> Ctx {
        int b0 = bt * 16;
        Ctx C;
        C.obs_pf = A.obs + ((size_t)BATCH + b0 + kgrp * 4) * NS + jt * 16 + wv * 4;
        C.ctl_p  = A.ctlp + ((size_t)b0 + kgrp * 4) * NA + arow;
        C.ab_p   = A.out_ab + ((size_t)b0 + wv * 4) * NS + lane * 4;
        C.aa_p   = A.out_aa + ((size_t)b0 + kgrp * 4) * NA + arow;
        C.obs0_p = A.obs + (size_t)(b0 + wv * 4) * NS + lane * 4;
        C.lg_ld  = A.lg + ((size_t)b0 + wv * 4) * NS + lane * 4;
        C.lg_st  = A.lg + ((size_t)b0 + (lane >> 2)) * NS + jt * 16 + (lane & 3) * 4;
        return C;
    };
    Ctx CA = mkctx(btA);
    Ctx CB = mkctx(btB);

    for (int s = 0; s < T_STEPS - 1; s++) {
        scan_phase(s, jt, lane, wv, kgrp, arow, CA, bfr, aph, apl, lp0, n4, PLb, out_t);
        scan_phase(s, jt, lane, wv, kgrp, arow, CB, bfr, aph, apl, lp0, n4, PLb, out_t);
    }

    // ---- epilogue: final softmax for both contexts (ab_p now at t = T-1)
    final_softmax(jt, lane, CA);
    final_softmax(jt, lane, CB);
}

extern "C" void kernel_launch(void* const* d_in, const int* in_sizes, int n_in,
                              void* d_out, int out_size, void* d_ws, size_t ws_size,
                              hipStream_t stream) {
    const float* x            = (const float*)d_in[0];
    const float* u            = (const float*)d_in[1];
    const float* obs_mu       = (const float*)d_in[2];
    const float* obs_lv       = (const float*)d_in[3];
    const float* ctl_mu       = (const float*)d_in[4];
    const float* ctl_lv       = (const float*)d_in[5];
    const float* trans_logits = (const float*)d_in[6];
    const float* pi0_logits   = (const float*)d_in[7];
    const float* act_prior    = (const float*)d_in[8];

    float* out_ab = (float*)d_out;
    float* out_aa = out_ab + (size_t)T_STEPS * BATCH * NS;

    char* w = (char*)d_ws;
    size_t off = 0;
    auto alloc = [&](size_t bytes) -> void* {
        void* pp = w + off;
        off += (bytes + 255) & ~(size_t)255;
        return pp;
    };
    float* WT   = (float*)alloc((size_t)256 * 256 * 4);
    float* Cs   = (float*)alloc(256 * 4);
    float* cw1  = (float*)alloc(256 * 4);
    float* cw2  = (float*)alloc(256 * 4);
    float* cc   = (float*)alloc(16 * 4);
    float* lpi0 = (float*)alloc(256 * 4);
    __hip_bfloat16* TRf = (__hip_bfloat16*)alloc((size_t)4096 * 256 * 2);
    __hip_bfloat16* APh = (__hip_bfloat16*)alloc((size_t)8 * 64 * 8 * 2);
    __hip_bfloat16* APl = (__hip_bfloat16*)alloc((size_t)8 * 64 * 8 * 2);
    float* obs  = (float*)alloc((size_t)T_STEPS * BATCH * NS * 4);
    float* ctlp = (float*)alloc((size_t)(T_STEPS - 1) * BATCH * NA * 4);
    float* lg   = (float*)alloc((size_t)4 * BATCH * NS * 4);   // 4 rotating buffers
    if (off > ws_size) return;   // insufficient scratch -> fail loudly

    k_init<<<256, 256, 0, stream>>>(lg);
    k_prep_obs<<<256, 128, 0, stream>>>(obs_mu, obs_lv, WT, Cs);
    k_prep_ctl<<<1, 256, 0, stream>>>(ctl_mu, ctl_lv, cw1, cw2, cc);
    k_prep_pi0<<<1, 64, 0, stream>>>(pi0_logits, lpi0);
    k_trans<<<1024, 256, 0, stream>>>(trans_logits, TRf);
    k_prep_ap<<<8, 64, 0, stream>>>(act_prior, APh, APl);
    k_obslp<<<1600, 256, 0, stream>>>(x, WT, Cs, obs);
    k_ctllp<<<3184, 256, 0, stream>>>(u, cw1, cw2, cc, ctlp);

    ScanArgs args;
    args.obs = obs; args.ctlp = ctlp; args.lpi0 = lpi0;
    args.TRf = TRf; args.APh = APh; args.APl = APl;
    args.lg = lg;
    args.out_ab = out_ab; args.out_aa = out_aa;
    k_scan_p<<<128, 256, 0, stream>>>(args);
}

// Round 12
// 1956.220 us; speedup vs baseline: 1.9341x; 1.9341x over previous
//
#include <hip/hip_runtime.h>
#include <hip/hip_bf16.h>
#include <stdint.h>

#define T_STEPS 200
#define BATCH   256
#define NS      256   // states S
#define NA      16    // actions A
#define DOBS    128
#define DCTL    16
#define LOG2PI  1.8378770664093453f
#define EPS_F   1e-6f

typedef float f32x4 __attribute__((ext_vector_type(4)));
typedef short s16x8 __attribute__((ext_vector_type(8)));
typedef short s16x4 __attribute__((ext_vector_type(4)));

static __device__ __forceinline__ unsigned short f2bf(float f) {
    union { float f; unsigned u; } v; v.f = f;
    unsigned u = v.u;
    u += 0x7fffu + ((u >> 16) & 1u);   // RNE
    return (unsigned short)(u >> 16);
}
static __device__ __forceinline__ float bf2f(unsigned short h) {
    union { unsigned u; float f; } v; v.u = ((unsigned)h) << 16;
    return v.f;
}

// ---- MALL-coherent (L1+L2 bypass) transport, canary-in-data (R7, proven) ----
static __device__ __forceinline__ void ld4_mall(const float* base,
                                                f32x4& a, f32x4& b, f32x4& c, f32x4& d) {
    asm volatile(
        "global_load_dwordx4 %0, %4, off offset:0 sc0 sc1\n\t"
        "global_load_dwordx4 %1, %4, off offset:1024 sc0 sc1\n\t"
        "global_load_dwordx4 %2, %4, off offset:2048 sc0 sc1\n\t"
        "global_load_dwordx4 %3, %4, off offset:3072 sc0 sc1\n\t"
        "s_waitcnt vmcnt(0)"
        : "=&v"(a), "=&v"(b), "=&v"(c), "=&v"(d)
        : "v"(base)
        : "memory");
}
static __device__ __forceinline__ void st_mall(float* p, f32x4 v) {
    asm volatile("global_store_dwordx4 %0, %1, off sc0 sc1" :: "v"(p), "v"(v) : "memory");
}

// ---- prep kernels ----
__global__ __launch_bounds__(128) void k_prep_obs(const float* __restrict__ obs_mu,
                                                  const float* __restrict__ obs_lv,
                                                  float* __restrict__ WT,
                                                  float* __restrict__ Cs) {
    int s = blockIdx.x, d = threadIdx.x;
    float lv = obs_lv[s * DOBS + d];
    float mu = obs_mu[s * DOBS + d];
    float iv = expf(-lv);
    WT[d * NS + s]          = -0.5f * iv;
    WT[(DOBS + d) * NS + s] = mu * iv;
    float part = mu * mu * iv + lv;
    for (int m = 1; m < 64; m <<= 1) part += __shfl_xor(part, m, 64);
    __shared__ float red[2];
    if ((threadIdx.x & 63) == 0) red[threadIdx.x >> 6] = part;
    __syncthreads();
    if (threadIdx.x == 0) Cs[s] = -0.5f * (red[0] + red[1] + DOBS * LOG2PI);
}

// W -> bf16 hi/lo B-fragment layout: frag[(ct*8+kk)*64+lane][e] =
// WT[kk*32 + (lane>>4)*8 + e][ct*16 + (lane&15)]
__global__ __launch_bounds__(64) void k_prep_wf(const float* __restrict__ WT,
                                                unsigned short* __restrict__ Wh,
                                                unsigned short* __restrict__ Wl) {
    int ct = blockIdx.x >> 3, kk = blockIdx.x & 7;
    int lane = threadIdx.x;
    for (int e = 0; e < 8; e++) {
        int dp = kk * 32 + (lane >> 4) * 8 + e;
        int s  = ct * 16 + (lane & 15);
        float v = WT[(size_t)dp * NS + s];
        unsigned short h = f2bf(v);
        size_t idx = ((size_t)(ct * 8 + kk) * 64 + lane) * 8 + e;
        Wh[idx] = h;
        Wl[idx] = f2bf(v - bf2f(h));
    }
}

__global__ __launch_bounds__(256) void k_prep_ctl(const float* __restrict__ cmu,
                                                  const float* __restrict__ clv,
                                                  float* __restrict__ cw1,
                                                  float* __restrict__ cw2,
                                                  float* __restrict__ cc) {
    int t = threadIdx.x;
    int a = t >> 4, d = t & 15;
    float lv = clv[a * DCTL + d];
    float mu = cmu[a * DCTL + d];
    float iv = expf(-lv);
    cw1[t] = -0.5f * iv;
    cw2[t] = mu * iv;
    float part = mu * mu * iv + lv;
    for (int m = 1; m < 16; m <<= 1) part += __shfl_xor(part, m, 64);
    if (d == 0) cc[a] = -0.5f * (part + DCTL * LOG2PI);
}

__global__ __launch_bounds__(64) void k_prep_pi0(const float* __restrict__ pl,
                                                 float* __restrict__ lpi0) {
    int l = threadIdx.x;
    float v[4]; float m = -1e30f;
    for (int k = 0; k < 4; k++) { v[k] = pl[l + 64 * k]; m = fmaxf(m, v[k]); }
    for (int mm = 1; mm < 64; mm <<= 1) m = fmaxf(m, __shfl_xor(m, mm, 64));
    float ssum = 0.f;
    for (int k = 0; k < 4; k++) ssum += expf(v[k] - m);
    for (int mm = 1; mm < 64; mm <<= 1) ssum += __shfl_xor(ssum, mm, 64);
    float ls = logf(ssum);
    for (int k = 0; k < 4; k++) lpi0[l + 64 * k] = v[k] - m - ls;
}

// NaN-fill the 4 rotating exchange buffers (MALL-visible)
__global__ __launch_bounds__(256) void k_init(float* __restrict__ lg) {
    int idx = blockIdx.x * 256 + threadIdx.x;
    float nv = __int_as_float(0x7FC00000);
    f32x4 n4 = {nv, nv, nv, nv};
    st_mall(lg + (size_t)idx * 4, n4);
}

__global__ __launch_bounds__(256) void k_trans(const float* __restrict__ tl,
                                               __hip_bfloat16* __restrict__ TRf) {
    int wave = threadIdx.x >> 6, lane = threadIdx.x & 63;
    int row = blockIdx.x * 4 + wave;        // (a,i) row in [0,4096)
    int a = row >> 8, i = row & 255;
    const float* src = tl + (size_t)row * NS;
    float v[4]; float m = -1e30f;
    for (int k = 0; k < 4; k++) { v[k] = src[lane + 64 * k]; m = fmaxf(m, v[k]); }
    for (int mm = 1; mm < 64; mm <<= 1) m = fmaxf(m, __shfl_xor(m, mm, 64));
    float ssum = 0.f; float ev[4];
    for (int k = 0; k < 4; k++) { ev[k] = expf(v[k] - m); ssum += ev[k]; }
    for (int mm = 1; mm < 64; mm <<= 1) ssum += __shfl_xor(ssum, mm, 64);
    float inv = 1.f / ssum;
    int kk = i >> 5;
    int lsub = ((i >> 3) & 3) * 16 + a;
    int e = i & 7;
    for (int k = 0; k < 4; k++) {
        int j = lane + 64 * k;
        float p = ev[k] * inv;
        TRf[((size_t)(j * 8 + kk) * 64 + lsub) * 8 + e] = __float2bfloat16(p);
    }
}

__global__ __launch_bounds__(64) void k_prep_ap(const float* __restrict__ ap,
                                                __hip_bfloat16* __restrict__ APh,
                                                __hip_bfloat16* __restrict__ APl) {
    int kk = blockIdx.x, lane = threadIdx.x;
    for (int e = 0; e < 8; e++) {
        int i = kk * 32 + (lane >> 4) * 8 + e;
        int a = lane & 15;
        float v = ap[i * NA + a];
        __hip_bfloat16 hb = __float2bfloat16(v);
        float hi = __bfloat162float(hb);
        APh[(kk * 64 + lane) * 8 + e] = hb;
        APl[(kk * 64 + lane) * 8 + e] = __float2bfloat16(v - hi);
    }
}

// ---- obs_lp via MFMA hi/lo: obs = F @ Wt + C, F = (x^2 || x), 3 passes ----
// Block = 64 rows x 256 cols, 256 threads / 4 waves, grid 800.
__global__ __launch_bounds__(256) void k_obslp_mfma(const float* __restrict__ x,
                                                    const unsigned short* __restrict__ Wh,
                                                    const unsigned short* __restrict__ Wl,
                                                    const float* __restrict__ Cs,
                                                    float* __restrict__ obs) {
    __shared__ __align__(16) char FhL[64 * 512];
    __shared__ __align__(16) char FlL[64 * 512];
    const int r0 = blockIdx.x * 64;
    const int tid = threadIdx.x;

    // stage F hi/lo (swizzled, same layout as scan's PLb)
    {
        int row = tid >> 2, c0 = (tid & 3) * 32;
        const float* xr = x + (size_t)(r0 + row) * DOBS + c0;
        int sw = (row & 7) << 4;
#pragma unroll
        for (int g = 0; g < 8; g++) {
            f32x4 v = *(const f32x4*)&xr[g * 4];
            s16x4 sqh, sql, lih, lil;
#pragma unroll
            for (int e = 0; e < 4; e++) {
                float sq = v[e] * v[e];
                unsigned short h1 = f2bf(sq);
                sqh[e] = (short)h1; sql[e] = (short)f2bf(sq - bf2f(h1));
                unsigned short h2 = f2bf(v[e]);
                lih[e] = (short)h2; lil[e] = (short)f2bf(v[e] - bf2f(h2));
            }
            int dp1 = (c0 + g * 4) * 2;
            int dp2 = (128 + c0 + g * 4) * 2;
            *(s16x4*)(FhL + row * 512 + (dp1 ^ sw)) = sqh;
            *(s16x4*)(FlL + row * 512 + (dp1 ^ sw)) = sql;
            *(s16x4*)(FhL + row * 512 + (dp2 ^ sw)) = lih;
            *(s16x4*)(FlL + row * 512 + (dp2 ^ sw)) = lil;
        }
    }
    __syncthreads();

    const int wv = tid >> 6, lane = tid & 63;
    const int kgrp = lane >> 4, arow = lane & 15;

    for (int rt = 0; rt < 4; rt++) {
        int rr = rt * 16 + arow;
        int sw = (rr & 7) << 4;
        s16x8 ah[8], al[8];
#pragma unroll
        for (int kk = 0; kk < 8; kk++) {
            ah[kk] = *(const s16x8*)(FhL + rr * 512 + ((kk * 64 + kgrp * 16) ^ sw));
            al[kk] = *(const s16x8*)(FlL + rr * 512 + ((kk * 64 + kgrp * 16) ^ sw));
        }
        f32x4 acc[4];
#pragma unroll
        for (int ci = 0; ci < 4; ci++) acc[ci] = (f32x4){0.f, 0.f, 0.f, 0.f};
#pragma unroll
        for (int ci = 0; ci < 4; ci++) {
            int ct = wv * 4 + ci;
#pragma unroll
            for (int kk = 0; kk < 8; kk++) {
                s16x8 bh = *((const s16x8*)Wh + (size_t)(ct * 8 + kk) * 64 + lane);
                s16x8 bl = *((const s16x8*)Wl + (size_t)(ct * 8 + kk) * 64 + lane);
                acc[ci] = __builtin_amdgcn_mfma_f32_16x16x32_bf16(ah[kk], bh, acc[ci], 0, 0, 0);
                acc[ci] = __builtin_amdgcn_mfma_f32_16x16x32_bf16(ah[kk], bl, acc[ci], 0, 0, 0);
                acc[ci] = __builtin_amdgcn_mfma_f32_16x16x32_bf16(al[kk], bh, acc[ci], 0, 0, 0);
            }
        }
#pragma unroll
        for (int ci = 0; ci < 4; ci++) {
            int ct = wv * 4 + ci;
            float cv = Cs[ct * 16 + arow];
#pragma unroll
            for (int r = 0; r < 4; r++)
                obs[(size_t)(r0 + rt * 16 + kgrp * 4 + r) * NS + ct * 16 + arow] =
                    acc[ci][r] + cv;
        }
    }
}

__global__ __launch_bounds__(256) void k_ctllp(const float* __restrict__ u,
                                               const float* __restrict__ cw1,
                                               const float* __restrict__ cw2,
                                               const float* __restrict__ cc,
                                               float* __restrict__ ctl) {
    int idx = blockIdx.x * 256 + threadIdx.x;
    int r = idx >> 4, a = idx & 15;
    const float* ur = u + (size_t)r * DCTL;
    const float* w1 = cw1 + a * DCTL;
    const float* w2 = cw2 + a * DCTL;
    float acc = cc[a];
#pragma unroll
    for (int d = 0; d < 16; d++) {
        float uv = ur[d];
        acc += uv * uv * w1[d] + uv * w2[d];
    }
    ctl[idx] = acc;
}

// ================= persistent scan kernel (R7, proven 1925us) =================
struct ScanArgs {
    const float* obs;
    const float* ctlp;
    const float* lpi0;
    const __hip_bfloat16* TRf;
    const __hip_bfloat16* APh;
    const __hip_bfloat16* APl;
    float* lg;        // 4 x 65536 floats
    float* out_ab;
    float* out_aa;
};

__global__ __launch_bounds__(256, 1) void k_scan_p(ScanArgs A) {
    const int bid  = blockIdx.x;
    const int bt   = bid >> 4;
    const int jt   = bid & 15;
    const int tid  = threadIdx.x;
    const int wv   = tid >> 6, lane = tid & 63;
    const int kgrp = lane >> 4, arow = lane & 15;
    const int b0   = bt * 16;

    __shared__ __align__(16) char PLb[16 * 512];
    __shared__ float out_t[16][16];

    const float nv = __int_as_float(0x7FC00000);
    const f32x4 n4 = {nv, nv, nv, nv};

    s16x8 bfr[4][8];
#pragma unroll
    for (int q = 0; q < 4; q++) {
        int ct = jt * 16 + wv * 4 + q;
#pragma unroll
        for (int kk = 0; kk < 8; kk++)
            bfr[q][kk] = *((const s16x8*)A.TRf + (size_t)(ct * 8 + kk) * 64 + lane);
    }
    s16x8 aph[8], apl[8];
#pragma unroll
    for (int kk = 0; kk < 8; kk++) {
        aph[kk] = *((const s16x8*)A.APh + kk * 64 + lane);
        apl[kk] = *((const s16x8*)A.APl + kk * 64 + lane);
    }
    f32x4 lp0 = *(const f32x4*)&A.lpi0[lane * 4];

    const float* obs_pf_p = A.obs + ((size_t)BATCH + b0 + kgrp * 4) * NS + jt * 16 + wv * 4;
    const float* ctl_p    = A.ctlp + ((size_t)b0 + kgrp * 4) * NA + arow;
    float*       ab_p     = A.out_ab + ((size_t)b0 + wv * 4) * NS + lane * 4;
    float*       aa_p     = A.out_aa + ((size_t)b0 + kgrp * 4) * NA + arow;
    const float* obs0_p   = A.obs + (size_t)(b0 + wv * 4) * NS + lane * 4;
    const float* lg_ld    = A.lg + ((size_t)b0 + wv * 4) * NS + lane * 4;
    float*       lg_st    = A.lg + ((size_t)b0 + (lane >> 2)) * NS + jt * 16 + (lane & 3) * 4;

    for (int s = 0; s < T_STEPS - 1; s++) {
        f32x4 obs_pfv[4];
#pragma unroll
        for (int r = 0; r < 4; r++)
            obs_pfv[r] = *(const f32x4*)&obs_pf_p[r * NS];
        float ctl_pf[4];
#pragma unroll
        for (int q = 0; q < 4; q++)
            ctl_pf[q] = ctl_p[q * NA];

        f32x4 V[4];
        if (s == 0) {
#pragma unroll
            for (int q = 0; q < 4; q++) {
                f32x4 o = *(const f32x4*)&obs0_p[q * NS];
                V[q] = o + lp0;
            }
        } else {
            const float* rb = lg_ld + ((size_t)(s & 3) << 16);
            for (;;) {
                ld4_mall(rb, V[0], V[1], V[2], V[3]);
                float chk = ((V[0].x + V[0].y) + (V[0].z + V[0].w))
                          + ((V[1].x + V[1].y) + (V[1].z + V[1].w))
                          + ((V[2].x + V[2].y) + (V[2].z + V[2].w))
                          + ((V[3].x + V[3].y) + (V[3].z + V[3].w));
                if (chk == chk) break;   // all finite -> all written
            }
        }

        if (s >= 2 && wv == 0)
            st_mall(lg_st + ((size_t)((s + 2) & 3) << 16), n4);

#pragma unroll
        for (int q = 0; q < 4; q++) {
            int r = wv * 4 + q;
            float m = fmaxf(fmaxf(V[q].x, V[q].y), fmaxf(V[q].z, V[q].w));
            for (int mm = 1; mm < 64; mm <<= 1) m = fmaxf(m, __shfl_xor(m, mm, 64));
            float e0 = __expf(V[q].x - m), e1 = __expf(V[q].y - m);
            float e2 = __expf(V[q].z - m), e3 = __expf(V[q].w - m);
            float ss = (e0 + e1) + (e2 + e3);
            for (int mm = 1; mm < 64; mm <<= 1) ss += __shfl_xor(ss, mm, 64);
            float inv = 1.f / ss;
            float p0 = e0 * inv, p1 = e1 * inv, p2 = e2 * inv, p3 = e3 * inv;
            if ((lane >> 2) == jt) {
                f32x4 pv = {p0, p1, p2, p3};
                *(f32x4*)&ab_p[q * NS] = pv;
            }
            s16x4 sv;
            sv[0] = (short)f2bf(p0); sv[1] = (short)f2bf(p1);
            sv[2] = (short)f2bf(p2); sv[3] = (short)f2bf(p3);
            *(s16x4*)(PLb + r * 512 + ((lane * 8) ^ ((r & 7) << 4))) = sv;
        }
        __syncthreads();

        s16x8 afr[8];
        {
            int sw = (arow & 7) << 4;
#pragma unroll
            for (int kk = 0; kk < 8; kk++)
                afr[kk] = *(const s16x8*)(PLb + arow * 512 + ((kk * 64 + kgrp * 16) ^ sw));
        }

        f32x4 gh = {0.f, 0.f, 0.f, 0.f}, gl = {0.f, 0.f, 0.f, 0.f};
#pragma unroll
        for (int kk = 0; kk < 8; kk++) {
            gh = __builtin_amdgcn_mfma_f32_16x16x32_bf16(afr[kk], aph[kk], gh, 0, 0, 0);
            gl = __builtin_amdgcn_mfma_f32_16x16x32_bf16(afr[kk], apl[kk], gl, 0, 0, 0);
        }
        float at[4];
#pragma unroll
        for (int q = 0; q < 4; q++) {
            float gv = gh[q] + gl[q];
            float m = gv;
            for (int mm = 1; mm < 16; mm <<= 1) m = fmaxf(m, __shfl_xor(m, mm, 64));
            float e1 = __expf(gv - m);
            float s1 = e1;
            for (int mm = 1; mm < 16; mm <<= 1) s1 += __shfl_xor(s1, mm, 64);
            float apr = e1 / s1;
            float al = ctl_pf[q] + __logf(apr + EPS_F);
            float m2 = al;
            for (int mm = 1; mm < 16; mm <<= 1) m2 = fmaxf(m2, __shfl_xor(m2, mm, 64));
            float e2 = __expf(al - m2);
            float s2 = e2;
            for (int mm = 1; mm < 16; mm <<= 1) s2 += __shfl_xor(s2, mm, 64);
            at[q] = e2 / s2;
            if (jt == 0)
                aa_p[q * NA] = at[q];
        }

#pragma unroll
        for (int q2 = 0; q2 < 4; q2++) {
            f32x4 acc = {0.f, 0.f, 0.f, 0.f};
#pragma unroll
            for (int kk = 0; kk < 8; kk++)
                acc = __builtin_amdgcn_mfma_f32_16x16x32_bf16(afr[kk], bfr[q2][kk], acc, 0, 0, 0);
#pragma unroll
            for (int r = 0; r < 4; r++) {
                float vv = acc[r] * at[r];
                for (int mm = 1; mm < 16; mm <<= 1) vv += __shfl_xor(vv, mm, 64);
                if (arow == 0)
                    out_t[kgrp * 4 + r][wv * 4 + q2] =
                        obs_pfv[r][q2] + __logf(vv + NS * EPS_F);
            }
        }
        __syncthreads();

        if (wv == 0) {
            f32x4 val = *(const f32x4*)&out_t[lane >> 2][(lane & 3) * 4];
            st_mall(lg_st + ((size_t)((s + 1) & 3) << 16), val);
        }
        obs_pf_p += (size_t)BATCH * NS;
        ctl_p    += (size_t)BATCH * NA;
        ab_p     += (size_t)BATCH * NS;
        aa_p     += (size_t)BATCH * NA;
    }

    // epilogue
    f32x4 V[4];
    {
        const float* rb = lg_ld + ((size_t)((T_STEPS - 1) & 3) << 16);
        for (;;) {
            ld4_mall(rb, V[0], V[1], V[2], V[3]);
            float chk = ((V[0].x + V[0].y) + (V[0].z + V[0].w))
                      + ((V[1].x + V[1].y) + (V[1].z + V[1].w))
                      + ((V[2].x + V[2].y) + (V[2].z + V[2].w))
                      + ((V[3].x + V[3].y) + (V[3].z + V[3].w));
            if (chk == chk) break;
        }
    }
#pragma unroll
    for (int q = 0; q < 4; q++) {
        float m = fmaxf(fmaxf(V[q].x, V[q].y), fmaxf(V[q].z, V[q].w));
        for (int mm = 1; mm < 64; mm <<= 1) m = fmaxf(m, __shfl_xor(m, mm, 64));
        float e0 = __expf(V[q].x - m), e1 = __expf(V[q].y - m);
        float e2 = __expf(V[q].z - m), e3 = __expf(V[q].w - m);
        float ss = (e0 + e1) + (e2 + e3);
        for (int mm = 1; mm < 64; mm <<= 1) ss += __shfl_xor(ss, mm, 64);
        float inv = 1.f / ss;
        if ((lane >> 2) == jt) {
            f32x4 pv = {e0 * inv, e1 * inv, e2 * inv, e3 * inv};
            *(f32x4*)&ab_p[q * NS] = pv;   // ab_p points at t = T-1
        }
    }
}

extern "C" void kernel_launch(void* const* d_in, const int* in_sizes, int n_in,
                              void* d_out, int out_size, void* d_ws, size_t ws_size,
                              hipStream_t stream) {
    const float* x            = (const float*)d_in[0];
    const float* u            = (const float*)d_in[1];
    const float* obs_mu       = (const float*)d_in[2];
    const float* obs_lv       = (const float*)d_in[3];
    const float* ctl_mu       = (const float*)d_in[4];
    const float* ctl_lv       = (const float*)d_in[5];
    const float* trans_logits = (const float*)d_in[6];
    const float* pi0_logits   = (const float*)d_in[7];
    const float* act_prior    = (const float*)d_in[8];

    float* out_ab = (float*)d_out;
    float* out_aa = out_ab + (size_t)T_STEPS * BATCH * NS;

    char* w = (char*)d_ws;
    size_t off = 0;
    auto alloc = [&](size_t bytes) -> void* {
        void* pp = w + off;
        off += (bytes + 255) & ~(size_t)255;
        return pp;
    };
    float* WT   = (float*)alloc((size_t)256 * 256 * 4);
    float* Cs   = (float*)alloc(256 * 4);
    float* cw1  = (float*)alloc(256 * 4);
    float* cw2  = (float*)alloc(256 * 4);
    float* cc   = (float*)alloc(16 * 4);
    float* lpi0 = (float*)alloc(256 * 4);
    __hip_bfloat16* TRf = (__hip_bfloat16*)alloc((size_t)4096 * 256 * 2);
    __hip_bfloat16* APh = (__hip_bfloat16*)alloc((size_t)8 * 64 * 8 * 2);
    __hip_bfloat16* APl = (__hip_bfloat16*)alloc((size_t)8 * 64 * 8 * 2);
    unsigned short* Wh  = (unsigned short*)alloc((size_t)16 * 8 * 64 * 8 * 2);
    unsigned short* Wl  = (unsigned short*)alloc((size_t)16 * 8 * 64 * 8 * 2);
    float* obs  = (float*)alloc((size_t)T_STEPS * BATCH * NS * 4);
    float* ctlp = (float*)alloc((size_t)(T_STEPS - 1) * BATCH * NA * 4);
    float* lg   = (float*)alloc((size_t)4 * BATCH * NS * 4);   // 4 rotating buffers
    if (off > ws_size) return;   // insufficient scratch -> fail loudly

    k_init<<<256, 256, 0, stream>>>(lg);
    k_prep_obs<<<256, 128, 0, stream>>>(obs_mu, obs_lv, WT, Cs);
    k_prep_wf<<<128, 64, 0, stream>>>(WT, Wh, Wl);
    k_prep_ctl<<<1, 256, 0, stream>>>(ctl_mu, ctl_lv, cw1, cw2, cc);
    k_prep_pi0<<<1, 64, 0, stream>>>(pi0_logits, lpi0);
    k_trans<<<1024, 256, 0, stream>>>(trans_logits, TRf);
    k_prep_ap<<<8, 64, 0, stream>>>(act_prior, APh, APl);
    k_obslp_mfma<<<800, 256, 0, stream>>>(x, Wh, Wl, Cs, obs);
    k_ctllp<<<3184, 256, 0, stream>>>(u, cw1, cw2, cc, ctlp);

    ScanArgs args;
    args.obs = obs; args.ctlp = ctlp; args.lpi0 = lpi0;
    args.TRf = TRf; args.APh = APh; args.APl = APl;
    args.lg = lg;
    args.out_ab = out_ab; args.out_aa = out_aa;
    k_scan_p<<<256, 256, 0, stream>>>(args);
}